// Round 6
// baseline (21760.794 us; speedup 1.0000x reference)
//
#include <hip/hip_runtime.h>
#include <hip/hip_bf16.h>
#include <math.h>

#define BB 256     // batch
#define TT 128     // timesteps
#define HH 256     // hidden
#define NBR 16     // batch rows per workgroup
#define BLK 512    // threads per block (8 waves)

typedef short bf8 __attribute__((ext_vector_type(8)));   // 8 bf16 (4 VGPRs)
typedef short s4v __attribute__((ext_vector_type(4)));   // 4 bf16 (8B)
typedef float f4  __attribute__((ext_vector_type(4)));   // MFMA accumulator
#define MFMA16(a,b,c) __builtin_amdgcn_mfma_f32_16x16x32_bf16((a), (b), (c), 0, 0, 0)

// ---- workspace layout (shorts), PAD covers register-prefetch overrun ----
#define WPAD 16384
constexpr size_t S_WC0 = 0;                                  // (2, 1024x384 swizzled)
constexpr size_t S_WC1 = S_WC0 + (size_t)2*1024*384 + WPAD;  // (2, 1024x768 swizzled)
constexpr size_t S_INP = S_WC1 + (size_t)2*1024*768 + WPAD;  // 1024x256 swizzled
constexpr size_t S_XP  = S_INP + (size_t)1024*256 + WPAD;    // 48x512 swizzled (3 waves)
constexpr size_t S_OUT = S_XP  + (size_t)48*512  + WPAD;     // 256x512 swizzled
constexpr size_t S_L0  = S_OUT + (size_t)256*512 + WPAD;     // (B,T,512) l0 output bf16
constexpr size_t S_END = S_L0 + (size_t)BB*TT*512;
constexpr size_t FOFF  = S_END * 2;                          // byte offset of f32 region
// f32 region:
constexpr size_t F_BSUM0 = 0;                 // (2,1024)
constexpr size_t F_BSUM1 = F_BSUM0 + 2048;    // (2,1024)
constexpr size_t F_H0    = F_BSUM1 + 2048;    // (2,B,256)
constexpr size_t F_C0    = F_H0 + 2*BB*256;
constexpr size_t F_H1    = F_C0 + 2*BB*256;
constexpr size_t F_C1    = F_H1 + 2*BB*256;
// total ~41.4 MB

__device__ __forceinline__ short f2bs(float v) {
    __hip_bfloat16 b = __float2bfloat16(v);
    short s; __builtin_memcpy(&s, &b, 2); return s;
}
__device__ __forceinline__ float bs2f(short s) {
    unsigned int u = ((unsigned int)(unsigned short)s) << 16;
    float f; __builtin_memcpy(&f, &u, 4); return f;
}
__device__ __forceinline__ float sigmoidf_(float x) { return 1.0f / (1.0f + __expf(-x)); }
__device__ __forceinline__ float softplusf_(float x) {
    return log1pf(__expf(-fabsf(x))) + fmaxf(x, 0.0f);
}
__device__ __forceinline__ float loadval(const float* p) { return *p; }
__device__ __forceinline__ float loadval(const short* p) { return bs2f(*p); }
__device__ __forceinline__ void storeval(float* p, float v) { *p = v; }
__device__ __forceinline__ void storeval(short* p, float v) { *p = f2bs(v); }

// fragment-block swizzle: dst idx -> (n,k) of source W[n][k]
// block = 512 shorts = 64 lanes x 8 shorts; wave-major, then k0-chunk, then tile
__device__ __forceinline__ void swz_nk(int idx, int KT, int TPW, int& n, int& k) {
    int chunk = TPW * 512;
    int per_wave = KT * chunk;
    int wv = idx / per_wave; int r = idx - wv * per_wave;
    int k0i = r / chunk; r -= k0i * chunk;
    int i = r >> 9; r &= 511;
    int ln = r >> 3; int j = r & 7;
    n = (wv * TPW + i) * 16 + (ln & 15);
    k = k0i * 32 + ((ln >> 4) << 3) + j;
}

// ---------------- prep: swizzle weights f32->bf16 fragment blocks, bsum, zero states ----------------
__global__ __launch_bounds__(256)
void prep3(const float* __restrict__ w_ih_l0, const float* __restrict__ w_hh_l0,
           const float* __restrict__ b_ih_l0, const float* __restrict__ b_hh_l0,
           const float* __restrict__ w_ih_l1, const float* __restrict__ w_hh_l1,
           const float* __restrict__ b_ih_l1, const float* __restrict__ b_hh_l1,
           const float* __restrict__ in_proj_w, const float* __restrict__ x_proj_w,
           const float* __restrict__ out_proj_w,
           short* __restrict__ wsu, float* __restrict__ wsf)
{
    const int nt = gridDim.x * blockDim.x;
    const int g0 = blockIdx.x * blockDim.x + threadIdx.x;

    // WC0: per dir 1024x384, KT=12, TPW=8
    for (int idx = g0; idx < 2*1024*384; idx += nt) {
        int dir = idx / (1024*384), rem = idx % (1024*384);
        int n, k; swz_nk(rem, 12, 8, n, k);
        float v = (k < 128) ? w_ih_l0[(size_t)dir*1024*128 + (size_t)n*128 + k]
                            : w_hh_l0[(size_t)dir*1024*256 + (size_t)n*256 + (k-128)];
        wsu[S_WC0 + idx] = f2bs(v);
    }
    // WC1: per dir 1024x768, KT=24, TPW=8
    for (int idx = g0; idx < 2*1024*768; idx += nt) {
        int dir = idx / (1024*768), rem = idx % (1024*768);
        int n, k; swz_nk(rem, 24, 8, n, k);
        float v = (k < 512) ? w_ih_l1[(size_t)dir*1024*512 + (size_t)n*512 + k]
                            : w_hh_l1[(size_t)dir*1024*256 + (size_t)n*256 + (k-512)];
        wsu[S_WC1 + idx] = f2bs(v);
    }
    // INP: 1024x256, KT=8, TPW=8
    for (int idx = g0; idx < 1024*256; idx += nt) {
        int n, k; swz_nk(idx, 8, 8, n, k);
        wsu[S_INP + idx] = f2bs(in_proj_w[(size_t)n*256 + k]);
    }
    // XP: 48x512 (3 waves), KT=16, TPW=1
    for (int idx = g0; idx < 48*512; idx += nt) {
        int n, k; swz_nk(idx, 16, 1, n, k);
        wsu[S_XP + idx] = f2bs(x_proj_w[(size_t)n*512 + k]);
    }
    // OUT: 256x512, KT=16, TPW=2
    for (int idx = g0; idx < 256*512; idx += nt) {
        int n, k; swz_nk(idx, 16, 2, n, k);
        wsu[S_OUT + idx] = f2bs(out_proj_w[(size_t)n*512 + k]);
    }
    for (int idx = g0; idx < 2048; idx += nt) {
        wsf[F_BSUM0 + idx] = b_ih_l0[idx] + b_hh_l0[idx];
        wsf[F_BSUM1 + idx] = b_ih_l1[idx] + b_hh_l1[idx];
    }
    for (int idx = g0; idx < 2*BB*256; idx += nt) {
        wsf[F_H0 + idx] = 0.0f;
        wsf[F_C0 + idx] = 0.0f;
    }
}

// ---- K-loop with register multi-buffer prefetch of swizzled B blocks ----
// W: wave-slice base (chunk c at W + c*TPW*512; block i at +i*512; lane frag at +ln*8)
// A: LDS row base (&sA[lr*stride]); chunk k-offset = k0i*32 + lq*8
template<int KT, int TPW, int DEPTH>
__device__ __forceinline__ void gemm_pf(const short* __restrict__ W,
                                        const short* __restrict__ A,
                                        f4* acc, int lnoff, int lq8)
{
    bf8 buf[DEPTH][TPW];
    #pragma unroll
    for (int d = 0; d < DEPTH; ++d)
        #pragma unroll
        for (int i = 0; i < TPW; ++i)
            buf[d][i] = *(const bf8*)(W + (d*TPW + i)*512 + lnoff);
    #pragma unroll
    for (int k0i = 0; k0i < KT; ++k0i) {
        const int slot = k0i % DEPTH;
        bf8 a = *(const bf8*)(A + k0i*32 + lq8);
        #pragma unroll
        for (int i = 0; i < TPW; ++i)
            acc[i] = MFMA16(a, buf[slot][i], acc[i]);
        const short* nb = W + (size_t)(k0i + DEPTH)*TPW*512;  // overruns into WPAD, never used
        #pragma unroll
        for (int i = 0; i < TPW; ++i)
            buf[slot][i] = *(const bf8*)(nb + i*512 + lnoff);
    }
}

// ---------------- MFMA layer kernel: one WG = 16 batch rows of one direction, loops all T ----------------
template<int DIN, typename TIn, typename TOut>
__global__ __launch_bounds__(BLK, 2)
void layer_mfma(const TIn* __restrict__ in,        // (B,T,DIN)
                TOut* __restrict__ out,             // (B,T,512): this dir writes [dir*256, +256)
                const short* __restrict__ wsu,
                const float* __restrict__ bsum_all, // (2,1024)
                const float* __restrict__ conv_w,   // (512,2) f32
                const float* __restrict__ conv_b,   // (512)
                const float* __restrict__ dtw,      // (512,16) f32
                const float* __restrict__ dtb_g,    // (512)
                const float* __restrict__ Dm_g,     // (512)
                const float* __restrict__ h_init, const float* __restrict__ c_init,  // (2,B,256)
                float* __restrict__ h_fin, float* __restrict__ c_fin)
{
    constexpr int KG = DIN + 256;          // gate GEMM K
    constexpr int KTG = KG / 32;
    const int tid = threadIdx.x;
    const int wv = tid >> 6, ln = tid & 63;
    const int lr = ln & 15, lq = ln >> 4;
    const int lnoff = ln * 8, lq8 = lq * 8;
    const int dir = blockIdx.y;
    const int b0 = blockIdx.x * NBR;

    const short* Wg   = wsu + ((DIN == 128) ? S_WC0 : S_WC1)
                        + (size_t)dir * 1024 * KG + (size_t)wv * (KTG * 8 * 512);
    const short* Winp = wsu + S_INP + (size_t)wv * (8 * 8 * 512);
    const short* Wxp  = wsu + S_XP  + (size_t)wv * (16 * 512);          // only wv<3
    const short* Wout = wsu + S_OUT + (size_t)wv * (16 * 2 * 512);

    __shared__ __attribute__((aligned(16))) short sA[16*776];    // [u(0..DIN) | h(DIN..DIN+256)]
    __shared__ __attribute__((aligned(16))) short sUm[16*264];   // mamba input bf16
    __shared__ __attribute__((aligned(16))) short sXm[16*520];   // xm, later y (in-place)
    __shared__ __attribute__((aligned(16))) short sZs[16*520];   // silu(z)
    __shared__ float sF[16*264], sG[16*264], sO[16*264];         // activated gates f32
    __shared__ float sXd[16*52];                                 // x_dbl f32
    __shared__ float sC[16*256];                                 // cell state f32
    __shared__ float sBsum[1024];
    __shared__ float sCw[512], sCb[512], sDtb[512], sDm[512];

    for (int idx = tid; idx < 1024; idx += BLK) sBsum[idx] = bsum_all[dir*1024 + idx];
    {   // BLK==512: one pass
        sCw[tid]  = conv_w[tid*2 + 1];
        sCb[tid]  = conv_b[tid];
        sDtb[tid] = dtb_g[tid];
        sDm[tid]  = Dm_g[tid];
    }
    for (int idx = tid; idx < 16*256; idx += BLK) {
        int r = idx >> 8, k = idx & 255;
        size_t src = ((size_t)dir*BB + b0 + r)*HH + k;
        sA[r*776 + DIN + k] = f2bs(h_init[src]);
        sC[idx] = c_init[src];
    }
    __syncthreads();

    for (int t = 0; t < TT; ++t) {
        const int t_in = dir ? (TT - 1 - t) : t;

        // ---- load u into A_cat[., 0..DIN), vectorized ----
        if constexpr (sizeof(TIn) == 2) {
            for (int v = tid; v < 16*DIN/8; v += BLK) {
                int r = v / (DIN/8), c8 = v % (DIN/8);
                *(bf8*)&sA[r*776 + c8*8] =
                    *(const bf8*)&((const short*)in)[((size_t)(b0 + r)*TT + t_in)*DIN + c8*8];
            }
        } else {
            for (int v = tid; v < 16*DIN/4; v += BLK) {
                int r = v / (DIN/4), c4 = v % (DIN/4);
                const float* src = &((const float*)in)[((size_t)(b0 + r)*TT + t_in)*DIN + c4*4];
                float4 f = *(const float4*)src;
                s4v p; p.x = f2bs(f.x); p.y = f2bs(f.y); p.z = f2bs(f.z); p.w = f2bs(f.w);
                *(s4v*)&sA[r*776 + c4*4] = p;
            }
        }
        __syncthreads();

        // ---- GEMM1: gates[16x1024] = [u|h] @ Wcat^T, K=KG ----
        {
            f4 acc[8];
            #pragma unroll
            for (int i = 0; i < 8; ++i) acc[i] = (f4){0.f,0.f,0.f,0.f};
            gemm_pf<KTG, 8, 2>(Wg, &sA[lr*776], acc, lnoff, lq8);
            if (wv < 2) {
                #pragma unroll
                for (int i = 0; i < 8; ++i) {
                    int col = wv*128 + i*16 + lr;
                    #pragma unroll
                    for (int j = 0; j < 4; ++j)
                        sUm[(lq*4+j)*264 + col] = f2bs(acc[i][j]);
                }
            } else {
                float* dst = (wv < 4) ? sF : (wv < 6) ? sG : sO;
                const bool istanh = (wv >= 4 && wv < 6);
                #pragma unroll
                for (int i = 0; i < 8; ++i) {
                    int col = wv*128 + i*16 + lr;
                    int kk = col & 255;
                    float bsv = sBsum[col];
                    #pragma unroll
                    for (int j = 0; j < 4; ++j) {
                        float v = acc[i][j] + bsv;
                        dst[(lq*4+j)*264 + kk] = istanh ? tanhf(v) : sigmoidf_(v);
                    }
                }
            }
        }
        __syncthreads();

        // ---- GEMM2: xz[16x1024] = um @ Winp^T, K=256; fuse conv+silu ----
        {
            f4 acc[8];
            #pragma unroll
            for (int i = 0; i < 8; ++i) acc[i] = (f4){0.f,0.f,0.f,0.f};
            gemm_pf<8, 8, 2>(Winp, &sUm[lr*264], acc, lnoff, lq8);
            #pragma unroll
            for (int i = 0; i < 8; ++i) {
                int col = wv*128 + i*16 + lr;
                if (col < 512) {
                    float cw = sCw[col], cbv = sCb[col];
                    #pragma unroll
                    for (int j = 0; j < 4; ++j) {
                        float v = fmaf(acc[i][j], cw, cbv);
                        sXm[(lq*4+j)*520 + col] = f2bs(v * sigmoidf_(v));
                    }
                } else {
                    int cz = col - 512;
                    #pragma unroll
                    for (int j = 0; j < 4; ++j) {
                        float z = acc[i][j];
                        sZs[(lq*4+j)*520 + cz] = f2bs(z * sigmoidf_(z));
                    }
                }
            }
        }
        __syncthreads();

        // ---- GEMM3: x_dbl[16x48] = xm @ Wxp^T, K=512 (waves 0..2) ----
        if (wv < 3) {
            f4 acc[1];
            acc[0] = (f4){0.f,0.f,0.f,0.f};
            gemm_pf<16, 1, 8>(Wxp, &sXm[lr*520], acc, lnoff, lq8);
            #pragma unroll
            for (int j = 0; j < 4; ++j)
                sXd[(lq*4+j)*52 + wv*16 + lr] = acc[0][j];
        }
        __syncthreads();

        // ---- phase4: delta/bc/y elementwise; y overwrites xm in-place ----
        {
            const int d = tid;
            float w16[16];
            #pragma unroll
            for (int p = 0; p < 16; ++p) w16[p] = dtw[d*16 + p];
            const float dtbv = sDtb[d], Dmv = sDm[d];
            for (int r = 0; r < 16; ++r) {
                float dp = dtbv;
                #pragma unroll
                for (int p = 0; p < 16; ++p) dp = fmaf(sXd[r*52 + p], w16[p], dp);
                float bc = 0.f;
                #pragma unroll
                for (int s = 0; s < 16; ++s) bc = fmaf(sXd[r*52 + 16 + s], sXd[r*52 + 32 + s], bc);
                float xmv = bs2f(sXm[r*520 + d]);
                float zsv = bs2f(sZs[r*520 + d]);
                float yv = fmaf(softplusf_(dp), bc, Dmv) * xmv * zsv;
                sXm[r*520 + d] = f2bs(yv);
            }
        }
        __syncthreads();

        // ---- GEMM4: mo[16x256] = y @ Woutp^T, K=512; fuse gate combine ----
        {
            f4 acc[2];
            acc[0] = (f4){0.f,0.f,0.f,0.f};
            acc[1] = (f4){0.f,0.f,0.f,0.f};
            gemm_pf<16, 2, 4>(Wout, &sXm[lr*520], acc, lnoff, lq8);
            #pragma unroll
            for (int i = 0; i < 2; ++i) {
                int k = wv*32 + i*16 + lr;
                float bsv = sBsum[k];
                #pragma unroll
                for (int j = 0; j < 4; ++j) {
                    int r = lq*4 + j;
                    float i_t = sigmoidf_(acc[i][j] + bsv);
                    float f_t = sF[r*264 + k];
                    float g_t = sG[r*264 + k];
                    float o_t = sO[r*264 + k];
                    float cv = fmaf(f_t, sC[r*256 + k], i_t * g_t);
                    sC[r*256 + k] = cv;
                    float hv = o_t * tanhf(cv);
                    sA[r*776 + DIN + k] = f2bs(hv);
                    storeval(&out[((size_t)(b0 + r)*TT + t_in)*512 + (size_t)dir*256 + k], hv);
                }
            }
        }
        // next u-load's barrier orders these writes before GEMM1 reads
    }

    __syncthreads();
    for (int idx = tid; idx < 16*256; idx += BLK) {
        int r = idx >> 8, k = idx & 255;
        size_t dst = ((size_t)dir*BB + b0 + r)*HH + k;
        h_fin[dst] = bs2f(sA[r*776 + DIN + k]);
        c_fin[dst] = sC[idx];
    }
}

extern "C" void kernel_launch(void* const* d_in, const int* in_sizes, int n_in,
                              void* d_out, int out_size, void* d_ws, size_t ws_size,
                              hipStream_t stream)
{
    const float* x          = (const float*)d_in[0];
    const float* w_ih_l0    = (const float*)d_in[1];
    const float* w_hh_l0    = (const float*)d_in[2];
    const float* b_ih_l0    = (const float*)d_in[3];
    const float* b_hh_l0    = (const float*)d_in[4];
    const float* w_ih_l1    = (const float*)d_in[5];
    const float* w_hh_l1    = (const float*)d_in[6];
    const float* b_ih_l1    = (const float*)d_in[7];
    const float* b_hh_l1    = (const float*)d_in[8];
    const float* in_proj_w  = (const float*)d_in[9];
    const float* conv_w     = (const float*)d_in[10];
    const float* conv_b     = (const float*)d_in[11];
    const float* x_proj_w   = (const float*)d_in[12];
    const float* dt_proj_w  = (const float*)d_in[13];
    const float* dt_proj_b  = (const float*)d_in[14];
    const float* D_m        = (const float*)d_in[15];
    const float* out_proj_w = (const float*)d_in[16];

    short* wsu = (short*)d_ws;
    float* wsf = (float*)((char*)d_ws + FOFF);

    prep3<<<512, 256, 0, stream>>>(
        w_ih_l0, w_hh_l0, b_ih_l0, b_hh_l0,
        w_ih_l1, w_hh_l1, b_ih_l1, b_hh_l1,
        in_proj_w, x_proj_w, out_proj_w, wsu, wsf);

    dim3 grid(BB / NBR, 2);

    // layer 0: x fp32 (DIN=128) -> l0out bf16; zero init states; finals -> H1/C1
    layer_mfma<128, float, short><<<grid, BLK, 0, stream>>>(
        x, wsu + S_L0, wsu,
        wsf + F_BSUM0, conv_w, conv_b, dt_proj_w, dt_proj_b, D_m,
        wsf + F_H0, wsf + F_C0, wsf + F_H1, wsf + F_C1);

    // layer 1: l0out bf16 (DIN=512) -> d_out fp32; init from H1/C1
    layer_mfma<512, short, float><<<grid, BLK, 0, stream>>>(
        wsu + S_L0, (float*)d_out, wsu,
        wsf + F_BSUM1, conv_w, conv_b, dt_proj_w, dt_proj_b, D_m,
        wsf + F_H1, wsf + F_C1, wsf + F_H0, wsf + F_C0);
}